// Round 11
// baseline (125.635 us; speedup 1.0000x reference)
//
#include <hip/hip_runtime.h>

// SAR quantizer: q, Q, Wn outputs.
// L=524288 rows, A=24 ADCs, B=8 bits, M=36 coefficient rows.
// VR = VREF = 1.8 / 2^3 = 0.225, noise scale = 0.01**0.5 = 0.1.
//
// R11 = R10 with the ADC-column bug fixed: with BLK=256 (not a multiple of
// 24), a must be gid % 24, not threadIdx.x % 24. (gid stride T=786432 is a
// multiple of 24, so a stays loop-invariant.)
// R10's A/B still in effect vs R9:
//  (a) 256-thread blocks, 3072 blocks -> 8 blocks/CU = true 32 waves/CU
//      (384-thread blocks capped at 5 blocks = 30 waves).
//  (b) plain cached stores (no nt) — the fill-proven 6.9 TB/s write path.
//      Read: ~90us => nt neutral; 75-85 => nt was throttling; >=96 => nt
//      was helping (revert).

#define L_TOT   524288
#define A_ADC   24
#define M_ROWS  36
#define B_BITS  8
#define BLK     256
#define NBLK    3072
#define NXCD    8
#define N_TOT   (L_TOT * A_ADC)          // 12,582,912
#define T_STR   (NBLK * BLK)             // 786,432 (multiple of 24); N = 16*T

typedef float f32x4 __attribute__((ext_vector_type(4)));

// XOR bank-quad swizzle (involution, bijective on [0,128)).
__device__ __forceinline__ int swz(int c) { return c ^ ((c >> 3) & 7); }

__global__ __launch_bounds__(BLK) void sar_kernel(
    const float* __restrict__ x,
    const float* __restrict__ W,
    const float* __restrict__ nz,
    float* __restrict__ out_q,
    float* __restrict__ out_Q,
    float* __restrict__ out_Wn)
{
    // Bijective XCD swizzle (NBLK % 8 == 0).
    const int bid = blockIdx.x;
    const int sb  = (bid & (NXCD - 1)) * (NBLK / NXCD) + (bid >> 3);

    const int gid = sb * BLK + threadIdx.x;   // < T_STR; 32-bit safe
    const int a = gid % 24;          // ADC column of element gid (+ m*T_STR)
    const int w = threadIdx.x >> 6;  // wave id in block (0..3)
    const int l = threadIdx.x & 63;  // lane

    __shared__ f32x4 stage[BLK / 64][2][128]; // 2 x 2KB per wave (16KB/blk)

    // Per-a coefficients: c[r] = (W[r][a] + noise[r][a]*0.1f) * 0.225f
    float c[M_ROWS];
#pragma unroll
    for (int r = 0; r < M_ROWS; ++r) {
        float wn = W[r * A_ADC + a] + nz[r * A_ADC + a] * 0.1f;
        c[r] = wn * 0.225f;
    }

    // Wn tail output (864 floats), once (gid is a bijection of thread id).
    if (gid < M_ROWS * A_ADC) {
        out_Wn[gid] = W[gid] + nz[gid] * 0.1f;
    }

    // Pipeline: xv0 = x[i], xv1 = x[i+T]; prefetch next pair each iter.
    float xv0 = x[gid];
    float xv1 = x[gid + T_STR];

    // Exactly 8 iterations; element m*T+gid covered with m=2k (A) and 2k+1 (B).
#pragma unroll 1
    for (int k = 0; k < 8; ++k) {
        const int i = gid + k * 2 * T_STR;

        // Prefetch the next pair FIRST (oldest position in VMEM queue).
        float xn0 = 0.0f, xn1 = 0.0f;
        if (k < 7) {                  // uniform branch
            xn0 = x[i + 2 * T_STR];
            xn1 = x[i + 3 * T_STR];
        }

        // Two independent SAR chains (bitmask state), interleaved for ILP.
        // sign(x-bs+1e-30) == (x>=bs ? +1 : -1) exactly (see R9 note);
        // t_k*c[m] == bit ? c[m] : 0.0f bit-exactly.
        unsigned m0 = 0u, m1 = 0u;    // bit j set => q_j = +1
        int m = M_ROWS - 1;
#pragma unroll
        for (int jj = 0; jj < B_BITS; ++jj) {
            const int j = B_BITS - 1 - jj;
            float bs0 = c[m], bs1 = c[m]; --m;   // Wn[m]*VREF
#pragma unroll
            for (int kk = j + 1; kk < B_BITS; ++kk) {
                bs0 += ((m0 >> kk) & 1u) ? c[m] : 0.0f;
                bs1 += ((m1 >> kk) & 1u) ? c[m] : 0.0f;
                --m;
            }
            if (xv0 >= bs0) m0 |= (1u << j);
            if (xv1 >= bs1) m1 |= (1u << j);
        }

        // q = sum_j bit_j * (0.225 * 2^j), ascending j (bit-exact vs ref).
        float acc0 = 0.0f, acc1 = 0.0f;
#pragma unroll
        for (int j = 0; j < B_BITS; ++j) {
            const float bwj = 0.225f * (float)(1 << j);
            acc0 += ((m0 >> j) & 1u) ? bwj : 0.0f;
            acc1 += ((m1 >> j) & 1u) ? bwj : 0.0f;
        }
        out_q[i] = acc0;
        out_q[i + T_STR] = acc1;

        // --- Q output via LDS staging (q_j = bit ? +1 : -1) ---
        f32x4 a0, a1, b0, b1;
#pragma unroll
        for (int j = 0; j < 4; ++j) {
            a0[j] = ((m0 >> j) & 1u)       ? 1.0f : -1.0f;
            a1[j] = ((m0 >> (j + 4)) & 1u) ? 1.0f : -1.0f;
            b0[j] = ((m1 >> j) & 1u)       ? 1.0f : -1.0f;
            b1[j] = ((m1 >> (j + 4)) & 1u) ? 1.0f : -1.0f;
        }
        const int c0 = 2 * l, c1 = 2 * l + 1;
        stage[w][0][swz(c0)] = a0;
        stage[w][0][swz(c1)] = a1;
        stage[w][1][swz(c0)] = b0;
        stage[w][1][swz(c1)] = b1;
        // wave-private; compiler inserts lgkmcnt before the readback.
        const int baseA = i - l;              // wave's first element (A)
        const int baseB = i + T_STR - l;      // (B)
        f32x4* QA = (f32x4*)out_Q + baseA * 2;   // f32x4 index space (x2/elem)
        f32x4* QB = (f32x4*)out_Q + baseB * 2;
        const int r0 = l, r1 = 64 + l;
        QA[r0] = stage[w][0][swz(r0)];
        QA[r1] = stage[w][0][swz(r1)];
        QB[r0] = stage[w][1][swz(r0)];
        QB[r1] = stage[w][1][swz(r1)];

        xv0 = xn0;
        xv1 = xn1;
    }
}

extern "C" void kernel_launch(void* const* d_in, const int* in_sizes, int n_in,
                              void* d_out, int out_size, void* d_ws, size_t ws_size,
                              hipStream_t stream) {
    const float* x  = (const float*)d_in[0];
    const float* W  = (const float*)d_in[1];
    const float* nz = (const float*)d_in[2];
    float* out = (float*)d_out;

    float* out_q  = out;
    float* out_Q  = out + (long long)N_TOT;
    float* out_Wn = out + (long long)N_TOT * 9;

    // 3072 blocks x 256 threads; stride T = 786432 (multiple of 24);
    // 8 unroll-2 iterations per thread; 8 blocks/CU = 32 waves/CU.
    sar_kernel<<<NBLK, BLK, 0, stream>>>(x, W, nz, out_q, out_Q, out_Wn);
}

// Round 12
// 93.511 us; speedup vs baseline: 1.3435x; 1.3435x over previous
//
#include <hip/hip_runtime.h>

// SAR quantizer: q, Q, Wn outputs.
// L=524288 rows, A=24 ADCs, B=8 bits, M=36 coefficient rows.
// VR = VREF = 1.8 / 2^3 = 0.225, noise scale = 0.01**0.5 = 0.1.
//
// R12 = R11 + nontemporal stores RESTORED (single change vs R11).
// R11's A/B proved nt stores were a ~35% win (95.6us with nt/30-wave vs
// 125.6us plain/32-wave): 442MB of write-once data through L2 churns the
// caches and evicts x; nt streams past. Geometry kept from R11:
// BLK=256 (a = gid%24 fix), NBLK=3072 -> 8 blocks/CU = 32 waves/CU.
//   vs R11: isolates nt (predict ~ -33us).
//   vs R9:  isolates occupancy 30->32 waves (predict ~ -6us -> ~89us).

#define L_TOT   524288
#define A_ADC   24
#define M_ROWS  36
#define B_BITS  8
#define BLK     256
#define NBLK    3072
#define NXCD    8
#define N_TOT   (L_TOT * A_ADC)          // 12,582,912
#define T_STR   (NBLK * BLK)             // 786,432 (multiple of 24); N = 16*T

typedef float f32x4 __attribute__((ext_vector_type(4)));

// XOR bank-quad swizzle (involution, bijective on [0,128)).
__device__ __forceinline__ int swz(int c) { return c ^ ((c >> 3) & 7); }

__global__ __launch_bounds__(BLK) void sar_kernel(
    const float* __restrict__ x,
    const float* __restrict__ W,
    const float* __restrict__ nz,
    float* __restrict__ out_q,
    float* __restrict__ out_Q,
    float* __restrict__ out_Wn)
{
    // Bijective XCD swizzle (NBLK % 8 == 0).
    const int bid = blockIdx.x;
    const int sb  = (bid & (NXCD - 1)) * (NBLK / NXCD) + (bid >> 3);

    const int gid = sb * BLK + threadIdx.x;   // < T_STR; 32-bit safe
    const int a = gid % 24;          // ADC column of element gid (+ m*T_STR)
    const int w = threadIdx.x >> 6;  // wave id in block (0..3)
    const int l = threadIdx.x & 63;  // lane

    __shared__ f32x4 stage[BLK / 64][2][128]; // 2 x 2KB per wave (16KB/blk)

    // Per-a coefficients: c[r] = (W[r][a] + noise[r][a]*0.1f) * 0.225f
    float c[M_ROWS];
#pragma unroll
    for (int r = 0; r < M_ROWS; ++r) {
        float wn = W[r * A_ADC + a] + nz[r * A_ADC + a] * 0.1f;
        c[r] = wn * 0.225f;
    }

    // Wn tail output (864 floats), once (gid is a bijection of thread id).
    if (gid < M_ROWS * A_ADC) {
        __builtin_nontemporal_store(W[gid] + nz[gid] * 0.1f, &out_Wn[gid]);
    }

    // Pipeline: xv0 = x[i], xv1 = x[i+T]; prefetch next pair each iter.
    float xv0 = x[gid];
    float xv1 = x[gid + T_STR];

    // Exactly 8 iterations; element m*T+gid covered with m=2k (A) and 2k+1 (B).
#pragma unroll 1
    for (int k = 0; k < 8; ++k) {
        const int i = gid + k * 2 * T_STR;

        // Prefetch the next pair FIRST (oldest position in VMEM queue).
        float xn0 = 0.0f, xn1 = 0.0f;
        if (k < 7) {                  // uniform branch
            xn0 = x[i + 2 * T_STR];
            xn1 = x[i + 3 * T_STR];
        }

        // Two independent SAR chains (bitmask state), interleaved for ILP.
        // sign(x-bs+1e-30) == (x>=bs ? +1 : -1) exactly (see R9 note);
        // t_k*c[m] == bit ? c[m] : 0.0f bit-exactly.
        unsigned m0 = 0u, m1 = 0u;    // bit j set => q_j = +1
        int m = M_ROWS - 1;
#pragma unroll
        for (int jj = 0; jj < B_BITS; ++jj) {
            const int j = B_BITS - 1 - jj;
            float bs0 = c[m], bs1 = c[m]; --m;   // Wn[m]*VREF
#pragma unroll
            for (int kk = j + 1; kk < B_BITS; ++kk) {
                bs0 += ((m0 >> kk) & 1u) ? c[m] : 0.0f;
                bs1 += ((m1 >> kk) & 1u) ? c[m] : 0.0f;
                --m;
            }
            if (xv0 >= bs0) m0 |= (1u << j);
            if (xv1 >= bs1) m1 |= (1u << j);
        }

        // q = sum_j bit_j * (0.225 * 2^j), ascending j (bit-exact vs ref).
        float acc0 = 0.0f, acc1 = 0.0f;
#pragma unroll
        for (int j = 0; j < B_BITS; ++j) {
            const float bwj = 0.225f * (float)(1 << j);
            acc0 += ((m0 >> j) & 1u) ? bwj : 0.0f;
            acc1 += ((m1 >> j) & 1u) ? bwj : 0.0f;
        }
        __builtin_nontemporal_store(acc0, &out_q[i]);
        __builtin_nontemporal_store(acc1, &out_q[i + T_STR]);

        // --- Q output via LDS staging (q_j = bit ? +1 : -1) ---
        f32x4 a0, a1, b0, b1;
#pragma unroll
        for (int j = 0; j < 4; ++j) {
            a0[j] = ((m0 >> j) & 1u)       ? 1.0f : -1.0f;
            a1[j] = ((m0 >> (j + 4)) & 1u) ? 1.0f : -1.0f;
            b0[j] = ((m1 >> j) & 1u)       ? 1.0f : -1.0f;
            b1[j] = ((m1 >> (j + 4)) & 1u) ? 1.0f : -1.0f;
        }
        const int c0 = 2 * l, c1 = 2 * l + 1;
        stage[w][0][swz(c0)] = a0;
        stage[w][0][swz(c1)] = a1;
        stage[w][1][swz(c0)] = b0;
        stage[w][1][swz(c1)] = b1;
        // wave-private; compiler inserts lgkmcnt before the readback.
        const int baseA = i - l;              // wave's first element (A)
        const int baseB = i + T_STR - l;      // (B)
        f32x4* QA = (f32x4*)out_Q + baseA * 2;   // f32x4 index space (x2/elem)
        f32x4* QB = (f32x4*)out_Q + baseB * 2;
        const int r0 = l, r1 = 64 + l;
        __builtin_nontemporal_store(stage[w][0][swz(r0)], &QA[r0]);
        __builtin_nontemporal_store(stage[w][0][swz(r1)], &QA[r1]);
        __builtin_nontemporal_store(stage[w][1][swz(r0)], &QB[r0]);
        __builtin_nontemporal_store(stage[w][1][swz(r1)], &QB[r1]);

        xv0 = xn0;
        xv1 = xn1;
    }
}

extern "C" void kernel_launch(void* const* d_in, const int* in_sizes, int n_in,
                              void* d_out, int out_size, void* d_ws, size_t ws_size,
                              hipStream_t stream) {
    const float* x  = (const float*)d_in[0];
    const float* W  = (const float*)d_in[1];
    const float* nz = (const float*)d_in[2];
    float* out = (float*)d_out;

    float* out_q  = out;
    float* out_Q  = out + (long long)N_TOT;
    float* out_Wn = out + (long long)N_TOT * 9;

    // 3072 blocks x 256 threads; stride T = 786432 (multiple of 24);
    // 8 unroll-2 iterations per thread; 8 blocks/CU = 32 waves/CU.
    sar_kernel<<<NBLK, BLK, 0, stream>>>(x, W, nz, out_q, out_Q, out_Wn);
}